// Round 5
// baseline (725.419 us; speedup 1.0000x reference)
//
#include <hip/hip_runtime.h>
#include <hip/hip_bf16.h>

#define T_DIM 512
#define B_DIM 16
#define D_DIM 1024
#define N_DIM 512

// c-fold: store S' = C*S so the exp2 argument is a single fma.
// C = 2*log2(e); tanh via exp2: tanh(x) = 1 - 2/(exp2(C*x)+1)
#define C_FOLD  2.885390082f
#define INV_C   0.3465735903f

typedef short s16x8 __attribute__((ext_vector_type(8)));
typedef float f32x4 __attribute__((ext_vector_type(4)));
typedef float f32x2 __attribute__((ext_vector_type(2)));

__device__ __forceinline__ unsigned short f2bf(float f) {
    unsigned u = __float_as_uint(f);
    unsigned r = (u + 0x7fffu + ((u >> 16) & 1u)) >> 16;
    return (unsigned short)r;
}

// sum over the 16 lanes of this DPP row, result broadcast to all 16.
// Pure VALU pipe - no LDS round trip (R7-proven).
__device__ __forceinline__ float reduce16(float x) {
    x += __int_as_float(__builtin_amdgcn_update_dpp(0, __float_as_int(x), 0xB1,  0xf, 0xf, true)); // quad_perm[1,0,3,2]
    x += __int_as_float(__builtin_amdgcn_update_dpp(0, __float_as_int(x), 0x4E,  0xf, 0xf, true)); // quad_perm[2,3,0,1]
    x += __int_as_float(__builtin_amdgcn_update_dpp(0, __float_as_int(x), 0x124, 0xf, 0xf, true)); // row_ror:4
    x += __int_as_float(__builtin_amdgcn_update_dpp(0, __float_as_int(x), 0x128, 0xf, 0xf, true)); // row_ror:8
    return x;
}

// ---------------- projection GEMM: C[m,n] = sum_d x[m,d] * W[n,d] ----------
__global__ __launch_bounds__(256) void proj_gemm(
    const float* __restrict__ x,
    const float* __restrict__ Wk,
    const float* __restrict__ Wv,
    const float* __restrict__ Wq,
    float* __restrict__ kbuf, float* __restrict__ vbuf, float* __restrict__ qbuf)
{
    const float* W = (blockIdx.z == 0) ? Wk : (blockIdx.z == 1) ? Wv : Wq;
    float* out = (blockIdx.z == 0) ? kbuf : (blockIdx.z == 1) ? vbuf : qbuf;

    __shared__ __align__(16) unsigned short As[64 * 40];
    __shared__ __align__(16) unsigned short Bs[64 * 40];

    const int tid  = threadIdx.x;
    const int m0   = blockIdx.x * 64;
    const int n0   = blockIdx.y * 64;
    const int wave = tid >> 6;
    const int lane = tid & 63;
    const int l15  = lane & 15;
    const int quad = lane >> 4;

    const int srow = tid >> 2;
    const int scol = (tid & 3) * 8;

    f32x4 acc[4];
#pragma unroll
    for (int i = 0; i < 4; ++i) acc[i] = (f32x4)0.0f;

    for (int k0 = 0; k0 < D_DIM; k0 += 32) {
        __syncthreads();
        {
            const float* srcA = &x[(size_t)(m0 + srow) * D_DIM + k0 + scol];
            float4 a0 = *(const float4*)srcA;
            float4 a1 = *(const float4*)(srcA + 4);
            uint4 pa;
            pa.x = (unsigned)f2bf(a0.x) | ((unsigned)f2bf(a0.y) << 16);
            pa.y = (unsigned)f2bf(a0.z) | ((unsigned)f2bf(a0.w) << 16);
            pa.z = (unsigned)f2bf(a1.x) | ((unsigned)f2bf(a1.y) << 16);
            pa.w = (unsigned)f2bf(a1.z) | ((unsigned)f2bf(a1.w) << 16);
            *(uint4*)&As[srow * 40 + scol] = pa;

            const float* srcB = &W[(size_t)(n0 + srow) * D_DIM + k0 + scol];
            float4 b0 = *(const float4*)srcB;
            float4 b1 = *(const float4*)(srcB + 4);
            uint4 pb;
            pb.x = (unsigned)f2bf(b0.x) | ((unsigned)f2bf(b0.y) << 16);
            pb.y = (unsigned)f2bf(b0.z) | ((unsigned)f2bf(b0.w) << 16);
            pb.z = (unsigned)f2bf(b1.x) | ((unsigned)f2bf(b1.y) << 16);
            pb.w = (unsigned)f2bf(b1.z) | ((unsigned)f2bf(b1.w) << 16);
            *(uint4*)&Bs[srow * 40 + scol] = pb;
        }
        __syncthreads();
        s16x8 af = *(const s16x8*)&As[(wave * 16 + l15) * 40 + quad * 8];
#pragma unroll
        for (int nt = 0; nt < 4; ++nt) {
            s16x8 bf = *(const s16x8*)&Bs[(nt * 16 + l15) * 40 + quad * 8];
            acc[nt] = __builtin_amdgcn_mfma_f32_16x16x32_bf16(af, bf, acc[nt], 0, 0, 0);
        }
    }
#pragma unroll
    for (int nt = 0; nt < 4; ++nt) {
#pragma unroll
        for (int rg = 0; rg < 4; ++rg) {
            int row = m0 + wave * 16 + quad * 4 + rg;
            int col = n0 + nt * 16 + l15;
            out[(size_t)row * N_DIM + col] = acc[nt][rg];
        }
    }
}

// ---------------- k row-normalization (in place) ---------------------------
__global__ __launch_bounds__(256) void knorm(float* __restrict__ kbuf)
{
    const int wave = threadIdx.x >> 6;
    const int lane = threadIdx.x & 63;
    const int row  = blockIdx.x * 4 + wave;
    float* p = &kbuf[(size_t)row * N_DIM + lane * 8];
    float4 a = *(const float4*)p;
    float4 b = *(const float4*)(p + 4);
    float s = a.x*a.x + a.y*a.y + a.z*a.z + a.w*a.w
            + b.x*b.x + b.y*b.y + b.z*b.z + b.w*b.w;
#pragma unroll
    for (int m = 1; m < 64; m <<= 1) s += __shfl_xor(s, m, 64);
    float inv = 1.0f / (sqrtf(s) + 1e-6f);
    a.x *= inv; a.y *= inv; a.z *= inv; a.w *= inv;
    b.x *= inv; b.y *= inv; b.z *= inv; b.w *= inv;
    *(float4*)p = a;
    *(float4*)(p + 4) = b;
}

// ---------------- sequential scan ------------------------------------------
// grid(32, 16): x = 16-row chunk, y = batch. block 256.
// R7 structure (16-lane row groups, pure-DPP reduce16, stride-36 staging,
// 1 barrier/step) proven at 617us with ZERO bank conflicts.
// R8: instruction diet. Model (R3-R7 invariant): time = VALU-busy/0.72 in
// every variant -> VALU-execution-bound; only op-count cuts pay.
//  (1) f32x4-native S/k/q: arithmetic directly on the b128-loaded vectors,
//      no f32x2 repack (kills extract moves).
//  (2) uniform SALU offset bump + constant lane offset for prefetch
//      addressing (replaces 3x per-lane 64-bit VGPR pointer bumps).
//  (3) v via broadcast global load per group (all 16 lanes same address,
//      L1-hit) - removes if(tid<16) exec-mask dances and the vs[] LDS
//      staging entirely.
__global__ __launch_bounds__(256) void scan_kernel(
    const float* __restrict__ kbuf, const float* __restrict__ vbuf,
    const float* __restrict__ qbuf, float* __restrict__ out)
{
    __shared__ __align__(16) float ks[2][576];
    __shared__ __align__(16) float qs[2][576];

    const int tid = threadIdx.x;
    const int l4  = tid & 15;          // lane within row-group: cols [32*l4, 32*l4+32)
    const int g   = tid >> 4;          // row-group id = local row 0..15
    const int b   = blockIdx.y;
    const int i0  = blockIdx.x * 16;

    // staging: thread writes logical cols {2tid, 2tid+1}: chunk=(2tid)>>5,
    // off=(2tid)&31 -> b64 write, conflict-free phases (R1-proven).
    const int wA  = 36 * (tid >> 4) + ((2 * tid) & 31);
    // read: lane l4 reads chunk l4 = cols [32*l4..32*l4+31], contiguous words.
    const int rA2 = 36 * l4;

    f32x4 S4[8];
#pragma unroll
    for (int u = 0; u < 8; ++u) S4[u] = (f32x4)0.0f;

    const int DT = B_DIM * N_DIM;          // 8192
    // uniform (SGPR) time offsets; lane offsets are loop-invariant VGPRs.
    size_t kqo = (size_t)b * N_DIM;        // k/q row base for time t+2
    size_t vo  = (size_t)b * N_DIM;        // v row base for time t+2
    const int kqlane = 2 * tid;
    const int vlane  = i0 + g;

    float2 pk, pq;
    float vA, vB, pvC = 0.0f;              // v(t), v(t+1), v(t+2) in flight
    {   // stage t=0 into buf0; prefetch t=1 into regs
        pk = *(const float2*)&kbuf[kqo + kqlane];
        pq = *(const float2*)&qbuf[kqo + kqlane];
        vA = vbuf[vo + vlane];
        *(float2*)&ks[0][wA] = pk;
        *(float2*)&qs[0][wA] = pq;
        kqo += DT; vo += DT;
        pk = *(const float2*)&kbuf[kqo + kqlane];
        pq = *(const float2*)&qbuf[kqo + kqlane];
        vB = vbuf[vo + vlane];
        kqo += DT; vo += DT;
    }
    __syncthreads();

    size_t oo = (size_t)b * N_DIM + i0 + g;   // output offset (bumped by DT)

    const f32x4 Cv4   = {C_FOLD, C_FOLD, C_FOLD, C_FOLD};
    const f32x4 M2Cv4 = {-2.0f * C_FOLD, -2.0f * C_FOLD, -2.0f * C_FOLD, -2.0f * C_FOLD};

    for (int t = 0; t < T_DIM; ++t) {
        const int cb = t & 1, nb = cb ^ 1;

        // stage t+1 (already in regs) into the other buffer
        if (t + 1 < T_DIM) {
            *(float2*)&ks[nb][wA] = pk;
            *(float2*)&qs[nb][wA] = pq;
        }
        // issue global prefetch for t+2 (uniform base, constant lane offset)
        if (t + 2 < T_DIM) {
            pk  = *(const float2*)&kbuf[kqo + kqlane];
            pq  = *(const float2*)&qbuf[kqo + kqlane];
            pvC = vbuf[vo + vlane];
        }
        kqo += DT; vo += DT;

        f32x4 k4[8], q4[8];
#pragma unroll
        for (int u = 0; u < 8; ++u) {
            k4[u] = *(const f32x4*)&ks[cb][rA2 + 4 * u];
            q4[u] = *(const f32x4*)&qs[cb][rA2 + 4 * u];
        }
        const float v0 = vA;

        // racc' = sum_j S'_ij k_j : 32 in-thread cols, then 16-lane DPP reduce
        f32x4 pA = (f32x4)0.0f, pB = (f32x4)0.0f;
#pragma unroll
        for (int u = 0; u < 8; u += 2) {
            pA += S4[u]     * k4[u];
            pB += S4[u + 1] * k4[u + 1];
        }
        pA += pB;
        const float racc = reduce16((pA.x + pA.z) + (pA.y + pA.w));

        const float dp = __builtin_fmaf(C_FOLD, v0, -racc);
        const f32x4 d4 = {dp, dp, dp, dp};

        // S'_new = C - 2C/(exp2(S' + dp'*k)+1);  sq' += S'_new * q
        // Tree rcp per 8 elems (pair of f32x4): 21 muls + 1 v_rcp (R6-proven).
        f32x4 sacc0 = (f32x4)0.0f, sacc1 = (f32x4)0.0f;
#pragma unroll
        for (int w = 0; w < 4; ++w) {
            f32x4 a0 = S4[2*w]     + d4 * k4[2*w];
            f32x4 a1 = S4[2*w + 1] + d4 * k4[2*w + 1];
            f32x4 f0 = { __builtin_amdgcn_exp2f(a0.x), __builtin_amdgcn_exp2f(a0.y),
                         __builtin_amdgcn_exp2f(a0.z), __builtin_amdgcn_exp2f(a0.w) };
            f32x4 f1 = { __builtin_amdgcn_exp2f(a1.x), __builtin_amdgcn_exp2f(a1.y),
                         __builtin_amdgcn_exp2f(a1.z), __builtin_amdgcn_exp2f(a1.w) };
            f0 = f0 + 1.0f; f1 = f1 + 1.0f;
            // product tree over the 8 scalars {f0,f1}.{x,y,z,w}
            f32x4 m  = f0 * f1;                       // 4 partial products
            f32x2 n2 = { m.x * m.z, m.y * m.w };      // products of 4
            float  P = n2.x * n2.y;                   // product of 8
            float rP = __builtin_amdgcn_rcpf(P);
            f32x2 rn2 = { n2.y * rP, n2.x * rP };     // {1/n2.x, 1/n2.y}
            f32x4 rm  = { rn2.x * m.z, rn2.y * m.w,   // 1/m.x, 1/m.y
                          rn2.x * m.x, rn2.y * m.y }; // 1/m.z, 1/m.w
            f32x4 r0 = rm * f1;                       // 1/f0
            f32x4 r1 = rm * f0;                       // 1/f1
            f32x4 n0 = Cv4 + r0 * M2Cv4;
            f32x4 n1 = Cv4 + r1 * M2Cv4;
            S4[2*w] = n0; S4[2*w + 1] = n1;
            sacc0 += n0 * q4[2*w];
            sacc1 += n1 * q4[2*w + 1];
        }
        sacc0 += sacc1;
        const float sq = reduce16((sacc0.x + sacc0.z) + (sacc0.y + sacc0.w));

        if (l4 == 0) {
            float s0 = sq * INV_C;
            float g0 = __builtin_amdgcn_rcpf(1.0f + __builtin_amdgcn_exp2f(-s0 * 1.44269504f));
            out[oo] = s0 * s0 * g0;
        }
        oo += DT;
        vA = vB; vB = pvC;
        __syncthreads();
    }

    // S_final (true scale) -> d_out[T*B*N + ((b*N + i)*N + col)]
    const size_t base = (size_t)T_DIM * B_DIM * N_DIM;
    const size_t so = base + ((size_t)b * N_DIM + i0 + g) * N_DIM + 32 * l4;
#pragma unroll
    for (int u = 0; u < 8; ++u) {
        f32x4 w0 = S4[u] * INV_C;
        *(f32x4*)&out[so + 4 * u] = w0;
    }
}

extern "C" void kernel_launch(void* const* d_in, const int* in_sizes, int n_in,
                              void* d_out, int out_size, void* d_ws, size_t ws_size,
                              hipStream_t stream) {
    const float* x  = (const float*)d_in[0];
    const float* Wk = (const float*)d_in[1];
    const float* Wv = (const float*)d_in[2];
    const float* Wq = (const float*)d_in[3];
    float* outp = (float*)d_out;

    const size_t MN = (size_t)T_DIM * B_DIM * N_DIM;
    float* kbuf = (float*)d_ws;
    float* vbuf = kbuf + MN;
    float* qbuf = vbuf + MN;

    proj_gemm<<<dim3(128, 8, 3), 256, 0, stream>>>(x, Wk, Wv, Wq, kbuf, vbuf, qbuf);
    knorm<<<2048, 256, 0, stream>>>(kbuf);
    scan_kernel<<<dim3(32, 16), 256, 0, stream>>>(kbuf, vbuf, qbuf, outp);
}

// Round 6
// 711.764 us; speedup vs baseline: 1.0192x; 1.0192x over previous
//
#include <hip/hip_runtime.h>
#include <hip/hip_bf16.h>

#define T_DIM 512
#define B_DIM 16
#define D_DIM 1024
#define N_DIM 512

// c-fold: store S' = C*S so the exp2 argument is a single fma.
// C = 2*log2(e); tanh via exp2: tanh(x) = 1 - 2/(exp2(C*x)+1)
#define C_FOLD  2.885390082f
#define INV_C   0.3465735903f

typedef short s16x8 __attribute__((ext_vector_type(8)));
typedef float f32x4 __attribute__((ext_vector_type(4)));
typedef float f32x2 __attribute__((ext_vector_type(2)));

// HW pair-converter: 2x f32 -> packed bf16 (RNE), replaces ~11 VALU ops of
// manual f2bf per pair with ONE v_cvt_pk_bf16_f32 (R9).
__device__ __forceinline__ unsigned cvt2bf(float lo, float hi) {
    unsigned r;
    asm("v_cvt_pk_bf16_f32 %0, %1, %2" : "=v"(r) : "v"(lo), "v"(hi));
    return r;
}

// sum over the 16 lanes of this DPP row, result broadcast to all 16.
// Pure VALU pipe - no LDS round trip (R7-proven).
__device__ __forceinline__ float reduce16(float x) {
    x += __int_as_float(__builtin_amdgcn_update_dpp(0, __float_as_int(x), 0xB1,  0xf, 0xf, true)); // quad_perm[1,0,3,2]
    x += __int_as_float(__builtin_amdgcn_update_dpp(0, __float_as_int(x), 0x4E,  0xf, 0xf, true)); // quad_perm[2,3,0,1]
    x += __int_as_float(__builtin_amdgcn_update_dpp(0, __float_as_int(x), 0x124, 0xf, 0xf, true)); // row_ror:4
    x += __int_as_float(__builtin_amdgcn_update_dpp(0, __float_as_int(x), 0x128, 0xf, 0xf, true)); // row_ror:8
    return x;
}

// ---------------- projection GEMM: C[m,n] = sum_d x[m,d] * W[n,d] ----------
__global__ __launch_bounds__(256) void proj_gemm(
    const float* __restrict__ x,
    const float* __restrict__ Wk,
    const float* __restrict__ Wv,
    const float* __restrict__ Wq,
    float* __restrict__ kbuf, float* __restrict__ vbuf, float* __restrict__ qbuf)
{
    const float* W = (blockIdx.z == 0) ? Wk : (blockIdx.z == 1) ? Wv : Wq;
    float* out = (blockIdx.z == 0) ? kbuf : (blockIdx.z == 1) ? vbuf : qbuf;

    __shared__ __align__(16) unsigned short As[64 * 40];
    __shared__ __align__(16) unsigned short Bs[64 * 40];

    const int tid  = threadIdx.x;
    const int m0   = blockIdx.x * 64;
    const int n0   = blockIdx.y * 64;
    const int wave = tid >> 6;
    const int lane = tid & 63;
    const int l15  = lane & 15;
    const int quad = lane >> 4;

    const int srow = tid >> 2;
    const int scol = (tid & 3) * 8;

    f32x4 acc[4];
#pragma unroll
    for (int i = 0; i < 4; ++i) acc[i] = (f32x4)0.0f;

    for (int k0 = 0; k0 < D_DIM; k0 += 32) {
        __syncthreads();
        {
            const float* srcA = &x[(size_t)(m0 + srow) * D_DIM + k0 + scol];
            float4 a0 = *(const float4*)srcA;
            float4 a1 = *(const float4*)(srcA + 4);
            uint4 pa;
            pa.x = cvt2bf(a0.x, a0.y);
            pa.y = cvt2bf(a0.z, a0.w);
            pa.z = cvt2bf(a1.x, a1.y);
            pa.w = cvt2bf(a1.z, a1.w);
            *(uint4*)&As[srow * 40 + scol] = pa;

            const float* srcB = &W[(size_t)(n0 + srow) * D_DIM + k0 + scol];
            float4 b0 = *(const float4*)srcB;
            float4 b1 = *(const float4*)(srcB + 4);
            uint4 pb;
            pb.x = cvt2bf(b0.x, b0.y);
            pb.y = cvt2bf(b0.z, b0.w);
            pb.z = cvt2bf(b1.x, b1.y);
            pb.w = cvt2bf(b1.z, b1.w);
            *(uint4*)&Bs[srow * 40 + scol] = pb;
        }
        __syncthreads();
        s16x8 af = *(const s16x8*)&As[(wave * 16 + l15) * 40 + quad * 8];
#pragma unroll
        for (int nt = 0; nt < 4; ++nt) {
            s16x8 bf = *(const s16x8*)&Bs[(nt * 16 + l15) * 40 + quad * 8];
            acc[nt] = __builtin_amdgcn_mfma_f32_16x16x32_bf16(af, bf, acc[nt], 0, 0, 0);
        }
    }
#pragma unroll
    for (int nt = 0; nt < 4; ++nt) {
#pragma unroll
        for (int rg = 0; rg < 4; ++rg) {
            int row = m0 + wave * 16 + quad * 4 + rg;
            int col = n0 + nt * 16 + l15;
            out[(size_t)row * N_DIM + col] = acc[nt][rg];
        }
    }
}

// ---------------- k row-normalization (in place) ---------------------------
__global__ __launch_bounds__(256) void knorm(float* __restrict__ kbuf)
{
    const int wave = threadIdx.x >> 6;
    const int lane = threadIdx.x & 63;
    const int row  = blockIdx.x * 4 + wave;
    float* p = &kbuf[(size_t)row * N_DIM + lane * 8];
    float4 a = *(const float4*)p;
    float4 b = *(const float4*)(p + 4);
    float s = a.x*a.x + a.y*a.y + a.z*a.z + a.w*a.w
            + b.x*b.x + b.y*b.y + b.z*b.z + b.w*b.w;
#pragma unroll
    for (int m = 1; m < 64; m <<= 1) s += __shfl_xor(s, m, 64);
    float inv = 1.0f / (sqrtf(s) + 1e-6f);
    a.x *= inv; a.y *= inv; a.z *= inv; a.w *= inv;
    b.x *= inv; b.y *= inv; b.z *= inv; b.w *= inv;
    *(float4*)p = a;
    *(float4*)(p + 4) = b;
}

// ---------------- sequential scan ------------------------------------------
// grid(32, 16): x = 16-row chunk, y = batch. block 256.
// R7-EXACT (617.6us proven, 0 bank conflicts). R8's f32x4/broadcast-v rewrite
// ADDED issued work (+2% busy, +5% time) and was reverted. Model: scan is
// VALU-execution-bound; time = busy/0.72 across all variants (R3-R8).
// 16-lane row groups: each DPP row owns ONE S-row x 32 cols/lane; pure-DPP
// reduce16 (no ds_swizzle). LDS: stride-36 staging (R1), b128 chunk reads,
// 2-way alias + broadcast = conflict-free. 1 barrier/step. Tree-rcp (R6).
__global__ __launch_bounds__(256) void scan_kernel(
    const float* __restrict__ kbuf, const float* __restrict__ vbuf,
    const float* __restrict__ qbuf, float* __restrict__ out)
{
    __shared__ __align__(16) float ks[2][576];
    __shared__ __align__(16) float qs[2][576];
    __shared__ float vs[2][16];

    const int tid = threadIdx.x;
    const int l4  = tid & 15;          // lane within row-group: cols [32*l4, 32*l4+32)
    const int g   = tid >> 4;          // row-group id = local row 0..15
    const int b   = blockIdx.y;
    const int i0  = blockIdx.x * 16;

    // staging: thread writes logical cols {2tid, 2tid+1}: chunk=(2tid)>>5,
    // off=(2tid)&31 -> b64 write, conflict-free phases (R1-proven).
    const int wA  = 36 * (tid >> 4) + ((2 * tid) & 31);
    // read: lane l4 reads chunk l4 = cols [32*l4..32*l4+31], contiguous words.
    const int rA2 = 36 * l4;

    f32x2 S2[16];
#pragma unroll
    for (int u = 0; u < 16; ++u) S2[u] = (f32x2)0.0f;

    const int DT = B_DIM * N_DIM;
    const float* kp = kbuf + (size_t)b * N_DIM + 2 * tid;
    const float* qp = qbuf + (size_t)b * N_DIM + 2 * tid;
    const float* vp = vbuf + (size_t)b * N_DIM + i0 + tid;

    float2 pk, pq; float pv = 0.0f;
    {   // stage t=0 into buf0; prefetch t=1 into regs
        pk = *(const float2*)kp; kp += DT;
        pq = *(const float2*)qp; qp += DT;
        if (tid < 16) pv = *vp;
        vp += DT;
        *(float2*)&ks[0][wA] = pk;
        *(float2*)&qs[0][wA] = pq;
        if (tid < 16) vs[0][tid] = pv;
        pk = *(const float2*)kp; kp += DT;
        pq = *(const float2*)qp; qp += DT;
        if (tid < 16) pv = *vp;
        vp += DT;
    }
    __syncthreads();

    float* op = out + (size_t)b * N_DIM + i0 + g;

    const f32x2 Cv   = {C_FOLD, C_FOLD};
    const f32x2 M2Cv = {-2.0f * C_FOLD, -2.0f * C_FOLD};

    for (int t = 0; t < T_DIM; ++t) {
        const int cb = t & 1, nb = cb ^ 1;

        // stage t+1 (already in regs) into the other buffer
        if (t + 1 < T_DIM) {
            *(float2*)&ks[nb][wA] = pk;
            *(float2*)&qs[nb][wA] = pq;
            if (tid < 16) vs[nb][tid] = pv;
        }
        // issue global prefetch for t+2
        if (t + 2 < T_DIM) {
            pk = *(const float2*)kp;
            pq = *(const float2*)qp;
            if (tid < 16) pv = *vp;
        }
        kp += DT; qp += DT; vp += DT;

        f32x2 k2[16], q2[16];
#pragma unroll
        for (int u = 0; u < 8; ++u) {
            f32x4 kv = *(const f32x4*)&ks[cb][rA2 + 4 * u];
            f32x4 qv = *(const f32x4*)&qs[cb][rA2 + 4 * u];
            k2[2*u] = kv.xy; k2[2*u+1] = kv.zw;
            q2[2*u] = qv.xy; q2[2*u+1] = qv.zw;
        }
        const float v0 = vs[cb][g];

        // racc' = sum_j S'_ij k_j : 32 in-thread cols, then 16-lane DPP reduce
        f32x2 p0 = (f32x2)0.0f, p1 = (f32x2)0.0f;
        f32x2 p2 = (f32x2)0.0f, p3 = (f32x2)0.0f;
#pragma unroll
        for (int w = 0; w < 4; ++w) {
            p0 += S2[4*w]     * k2[4*w];
            p1 += S2[4*w + 1] * k2[4*w + 1];
            p2 += S2[4*w + 2] * k2[4*w + 2];
            p3 += S2[4*w + 3] * k2[4*w + 3];
        }
        p0 += p1; p2 += p3; p0 += p2;
        const float racc = reduce16(p0.x + p0.y);

        const float dp = __builtin_fmaf(C_FOLD, v0, -racc);
        const f32x2 d0 = {dp, dp};

        // S'_new = C - 2C/(exp2(S' + dp'*k)+1);  sq' += S'_new * q
        // Grouped rcp (R6): one v_rcp per 8 elems via prefix/suffix products.
        f32x2 sacc0 = (f32x2)0.0f, sacc1 = (f32x2)0.0f;
#pragma unroll
        for (int w = 0; w < 4; ++w) {
            f32x2 a0 = S2[4*w]     + d0 * k2[4*w];
            f32x2 a1 = S2[4*w + 1] + d0 * k2[4*w + 1];
            f32x2 a2 = S2[4*w + 2] + d0 * k2[4*w + 2];
            f32x2 a3 = S2[4*w + 3] + d0 * k2[4*w + 3];
            f32x2 f0 = { __builtin_amdgcn_exp2f(a0.x), __builtin_amdgcn_exp2f(a0.y) };
            f32x2 f1 = { __builtin_amdgcn_exp2f(a1.x), __builtin_amdgcn_exp2f(a1.y) };
            f32x2 f2 = { __builtin_amdgcn_exp2f(a2.x), __builtin_amdgcn_exp2f(a2.y) };
            f32x2 f3 = { __builtin_amdgcn_exp2f(a3.x), __builtin_amdgcn_exp2f(a3.y) };
            f0 = f0 + 1.0f; f1 = f1 + 1.0f; f2 = f2 + 1.0f; f3 = f3 + 1.0f;
            // product tree over the 8 scalars {f0,f1,f2,f3}.{x,y}
            f32x2 m0 = f0 * f1;
            f32x2 m1 = f2 * f3;
            f32x2 qq = m0 * m1;
            float rP = __builtin_amdgcn_rcpf(qq.x * qq.y);
            f32x2 rq  = { qq.y * rP, qq.x * rP };   // {1/qq.x, 1/qq.y}
            f32x2 rm0 = rq * m1;                     // {1/m0.x, 1/m0.y}
            f32x2 rm1 = rq * m0;                     // {1/m1.x, 1/m1.y}
            f32x2 r0 = rm0 * f1;                     // 1/f0
            f32x2 r1 = rm0 * f0;                     // 1/f1
            f32x2 r2 = rm1 * f3;                     // 1/f2
            f32x2 r3 = rm1 * f2;                     // 1/f3
            f32x2 n0 = Cv + r0 * M2Cv;
            f32x2 n1 = Cv + r1 * M2Cv;
            f32x2 n2 = Cv + r2 * M2Cv;
            f32x2 n3 = Cv + r3 * M2Cv;
            S2[4*w] = n0; S2[4*w + 1] = n1; S2[4*w + 2] = n2; S2[4*w + 3] = n3;
            sacc0 += n0 * q2[4*w]     + n2 * q2[4*w + 2];
            sacc1 += n1 * q2[4*w + 1] + n3 * q2[4*w + 3];
        }
        sacc0 += sacc1;
        const float sq = reduce16(sacc0.x + sacc0.y);

        if (l4 == 0) {
            float s0 = sq * INV_C;
            float g0 = __builtin_amdgcn_rcpf(1.0f + __builtin_amdgcn_exp2f(-s0 * 1.44269504f));
            op[0] = s0 * s0 * g0;
        }
        op += DT;
        __syncthreads();
    }

    // S_final (true scale) -> d_out[T*B*N + ((b*N + i)*N + col)]
    const size_t base = (size_t)T_DIM * B_DIM * N_DIM;
    const size_t so = base + ((size_t)b * N_DIM + i0 + g) * N_DIM + 32 * l4;
#pragma unroll
    for (int u = 0; u < 8; ++u) {
        float4 w0;
        w0.x = S2[2*u].x   * INV_C; w0.y = S2[2*u].y   * INV_C;
        w0.z = S2[2*u+1].x * INV_C; w0.w = S2[2*u+1].y * INV_C;
        *(float4*)&out[so + 4 * u] = w0;
    }
}

extern "C" void kernel_launch(void* const* d_in, const int* in_sizes, int n_in,
                              void* d_out, int out_size, void* d_ws, size_t ws_size,
                              hipStream_t stream) {
    const float* x  = (const float*)d_in[0];
    const float* Wk = (const float*)d_in[1];
    const float* Wv = (const float*)d_in[2];
    const float* Wq = (const float*)d_in[3];
    float* outp = (float*)d_out;

    const size_t MN = (size_t)T_DIM * B_DIM * N_DIM;
    float* kbuf = (float*)d_ws;
    float* vbuf = kbuf + MN;
    float* qbuf = vbuf + MN;

    proj_gemm<<<dim3(128, 8, 3), 256, 0, stream>>>(x, Wk, Wv, Wq, kbuf, vbuf, qbuf);
    knorm<<<2048, 256, 0, stream>>>(kbuf);
    scan_kernel<<<dim3(32, 16), 256, 0, stream>>>(kbuf, vbuf, qbuf, outp);
}

// Round 7
// 672.645 us; speedup vs baseline: 1.0785x; 1.0582x over previous
//
#include <hip/hip_runtime.h>
#include <hip/hip_bf16.h>

#define T_DIM 512
#define B_DIM 16
#define D_DIM 1024
#define N_DIM 512

// c-fold: store S' = C*S so the exp2 argument is a single fma.
// C = 2*log2(e); tanh via exp2: tanh(x) = 1 - 2/(exp2(C*x)+1)
#define C_FOLD  2.885390082f
#define INV_C   0.3465735903f

typedef short s16x8 __attribute__((ext_vector_type(8)));
typedef float f32x4 __attribute__((ext_vector_type(4)));
typedef float f32x2 __attribute__((ext_vector_type(2)));

// HW pair-converter: 2x f32 -> packed bf16 (RNE), one VALU op per pair (R9-proven).
__device__ __forceinline__ unsigned cvt2bf(float lo, float hi) {
    unsigned r;
    asm("v_cvt_pk_bf16_f32 %0, %1, %2" : "=v"(r) : "v"(lo), "v"(hi));
    return r;
}

// sum over the 16 lanes of this DPP row, result broadcast to all 16.
// Pure VALU pipe - no LDS round trip (R7-proven).
__device__ __forceinline__ float reduce16(float x) {
    x += __int_as_float(__builtin_amdgcn_update_dpp(0, __float_as_int(x), 0xB1,  0xf, 0xf, true)); // quad_perm[1,0,3,2]
    x += __int_as_float(__builtin_amdgcn_update_dpp(0, __float_as_int(x), 0x4E,  0xf, 0xf, true)); // quad_perm[2,3,0,1]
    x += __int_as_float(__builtin_amdgcn_update_dpp(0, __float_as_int(x), 0x124, 0xf, 0xf, true)); // row_ror:4
    x += __int_as_float(__builtin_amdgcn_update_dpp(0, __float_as_int(x), 0x128, 0xf, 0xf, true)); // row_ror:8
    return x;
}

// ---------------- fused projection GEMM ------------------------------------
// R10: one block computes the 64x64 (m,n) tile for ALL THREE projections.
// vs R9 (gridDim.z=3): x-tile staged+converted ONCE instead of 3x, barriers
// per output-FLOP 6->2, per-thread staged elems/K-step 48->32, global load
// instrs 12->8. MFMA count unchanged (12/wave/K-step). LDS 4x5KB = 20KB.
__global__ __launch_bounds__(256) void proj_gemm(
    const float* __restrict__ x,
    const float* __restrict__ Wk,
    const float* __restrict__ Wv,
    const float* __restrict__ Wq,
    float* __restrict__ kbuf, float* __restrict__ vbuf, float* __restrict__ qbuf)
{
    __shared__ __align__(16) unsigned short As[64 * 40];
    __shared__ __align__(16) unsigned short Bk[64 * 40];
    __shared__ __align__(16) unsigned short Bv[64 * 40];
    __shared__ __align__(16) unsigned short Bq[64 * 40];

    const int tid  = threadIdx.x;
    const int m0   = blockIdx.x * 64;
    const int n0   = blockIdx.y * 64;
    const int wave = tid >> 6;
    const int lane = tid & 63;
    const int l15  = lane & 15;
    const int quad = lane >> 4;

    const int srow = tid >> 2;
    const int scol = (tid & 3) * 8;

    f32x4 ak[4], av[4], aq[4];
#pragma unroll
    for (int i = 0; i < 4; ++i) { ak[i] = (f32x4)0.0f; av[i] = (f32x4)0.0f; aq[i] = (f32x4)0.0f; }

    const size_t aoff = (size_t)(m0 + srow) * D_DIM + scol;
    const size_t boff = (size_t)(n0 + srow) * D_DIM + scol;

    for (int k0 = 0; k0 < D_DIM; k0 += 32) {
        __syncthreads();
        {
            const float* srcA = &x[aoff + k0];
            float4 a0 = *(const float4*)srcA;
            float4 a1 = *(const float4*)(srcA + 4);
            uint4 pa;
            pa.x = cvt2bf(a0.x, a0.y);
            pa.y = cvt2bf(a0.z, a0.w);
            pa.z = cvt2bf(a1.x, a1.y);
            pa.w = cvt2bf(a1.z, a1.w);
            *(uint4*)&As[srow * 40 + scol] = pa;

            const float* sk = &Wk[boff + k0];
            float4 b0 = *(const float4*)sk;
            float4 b1 = *(const float4*)(sk + 4);
            uint4 pb;
            pb.x = cvt2bf(b0.x, b0.y);
            pb.y = cvt2bf(b0.z, b0.w);
            pb.z = cvt2bf(b1.x, b1.y);
            pb.w = cvt2bf(b1.z, b1.w);
            *(uint4*)&Bk[srow * 40 + scol] = pb;

            const float* sv = &Wv[boff + k0];
            b0 = *(const float4*)sv;
            b1 = *(const float4*)(sv + 4);
            pb.x = cvt2bf(b0.x, b0.y);
            pb.y = cvt2bf(b0.z, b0.w);
            pb.z = cvt2bf(b1.x, b1.y);
            pb.w = cvt2bf(b1.z, b1.w);
            *(uint4*)&Bv[srow * 40 + scol] = pb;

            const float* sq = &Wq[boff + k0];
            b0 = *(const float4*)sq;
            b1 = *(const float4*)(sq + 4);
            pb.x = cvt2bf(b0.x, b0.y);
            pb.y = cvt2bf(b0.z, b0.w);
            pb.z = cvt2bf(b1.x, b1.y);
            pb.w = cvt2bf(b1.z, b1.w);
            *(uint4*)&Bq[srow * 40 + scol] = pb;
        }
        __syncthreads();
        s16x8 af = *(const s16x8*)&As[(wave * 16 + l15) * 40 + quad * 8];
#pragma unroll
        for (int nt = 0; nt < 4; ++nt) {
            s16x8 bk = *(const s16x8*)&Bk[(nt * 16 + l15) * 40 + quad * 8];
            ak[nt] = __builtin_amdgcn_mfma_f32_16x16x32_bf16(af, bk, ak[nt], 0, 0, 0);
            s16x8 bv = *(const s16x8*)&Bv[(nt * 16 + l15) * 40 + quad * 8];
            av[nt] = __builtin_amdgcn_mfma_f32_16x16x32_bf16(af, bv, av[nt], 0, 0, 0);
            s16x8 bq = *(const s16x8*)&Bq[(nt * 16 + l15) * 40 + quad * 8];
            aq[nt] = __builtin_amdgcn_mfma_f32_16x16x32_bf16(af, bq, aq[nt], 0, 0, 0);
        }
    }
#pragma unroll
    for (int nt = 0; nt < 4; ++nt) {
#pragma unroll
        for (int rg = 0; rg < 4; ++rg) {
            int row = m0 + wave * 16 + quad * 4 + rg;
            int col = n0 + nt * 16 + l15;
            kbuf[(size_t)row * N_DIM + col] = ak[nt][rg];
            vbuf[(size_t)row * N_DIM + col] = av[nt][rg];
            qbuf[(size_t)row * N_DIM + col] = aq[nt][rg];
        }
    }
}

// ---------------- k row-normalization (in place) ---------------------------
__global__ __launch_bounds__(256) void knorm(float* __restrict__ kbuf)
{
    const int wave = threadIdx.x >> 6;
    const int lane = threadIdx.x & 63;
    const int row  = blockIdx.x * 4 + wave;
    float* p = &kbuf[(size_t)row * N_DIM + lane * 8];
    float4 a = *(const float4*)p;
    float4 b = *(const float4*)(p + 4);
    float s = a.x*a.x + a.y*a.y + a.z*a.z + a.w*a.w
            + b.x*b.x + b.y*b.y + b.z*b.z + b.w*b.w;
#pragma unroll
    for (int m = 1; m < 64; m <<= 1) s += __shfl_xor(s, m, 64);
    float inv = 1.0f / (sqrtf(s) + 1e-6f);
    a.x *= inv; a.y *= inv; a.z *= inv; a.w *= inv;
    b.x *= inv; b.y *= inv; b.z *= inv; b.w *= inv;
    *(float4*)p = a;
    *(float4*)(p + 4) = b;
}

// ---------------- sequential scan ------------------------------------------
// grid(32, 16): x = 16-row chunk, y = batch. block 256.
// R7-EXACT (617.6us best; 642 in R9's run = clock variance +-4%, counters
// identical). Model: VALU-execution-bound; trans ops ~8 issue-cyc (R6 fit),
// so tree-rcp stays. 16-lane row groups, pure-DPP reduce16, stride-36
// staging, 1 barrier/step, 0 bank conflicts.
__global__ __launch_bounds__(256) void scan_kernel(
    const float* __restrict__ kbuf, const float* __restrict__ vbuf,
    const float* __restrict__ qbuf, float* __restrict__ out)
{
    __shared__ __align__(16) float ks[2][576];
    __shared__ __align__(16) float qs[2][576];
    __shared__ float vs[2][16];

    const int tid = threadIdx.x;
    const int l4  = tid & 15;          // lane within row-group: cols [32*l4, 32*l4+32)
    const int g   = tid >> 4;          // row-group id = local row 0..15
    const int b   = blockIdx.y;
    const int i0  = blockIdx.x * 16;

    // staging: thread writes logical cols {2tid, 2tid+1}: chunk=(2tid)>>5,
    // off=(2tid)&31 -> b64 write, conflict-free phases (R1-proven).
    const int wA  = 36 * (tid >> 4) + ((2 * tid) & 31);
    // read: lane l4 reads chunk l4 = cols [32*l4..32*l4+31], contiguous words.
    const int rA2 = 36 * l4;

    f32x2 S2[16];
#pragma unroll
    for (int u = 0; u < 16; ++u) S2[u] = (f32x2)0.0f;

    const int DT = B_DIM * N_DIM;
    const float* kp = kbuf + (size_t)b * N_DIM + 2 * tid;
    const float* qp = qbuf + (size_t)b * N_DIM + 2 * tid;
    const float* vp = vbuf + (size_t)b * N_DIM + i0 + tid;

    float2 pk, pq; float pv = 0.0f;
    {   // stage t=0 into buf0; prefetch t=1 into regs
        pk = *(const float2*)kp; kp += DT;
        pq = *(const float2*)qp; qp += DT;
        if (tid < 16) pv = *vp;
        vp += DT;
        *(float2*)&ks[0][wA] = pk;
        *(float2*)&qs[0][wA] = pq;
        if (tid < 16) vs[0][tid] = pv;
        pk = *(const float2*)kp; kp += DT;
        pq = *(const float2*)qp; qp += DT;
        if (tid < 16) pv = *vp;
        vp += DT;
    }
    __syncthreads();

    float* op = out + (size_t)b * N_DIM + i0 + g;

    const f32x2 Cv   = {C_FOLD, C_FOLD};
    const f32x2 M2Cv = {-2.0f * C_FOLD, -2.0f * C_FOLD};

    for (int t = 0; t < T_DIM; ++t) {
        const int cb = t & 1, nb = cb ^ 1;

        // stage t+1 (already in regs) into the other buffer
        if (t + 1 < T_DIM) {
            *(float2*)&ks[nb][wA] = pk;
            *(float2*)&qs[nb][wA] = pq;
            if (tid < 16) vs[nb][tid] = pv;
        }
        // issue global prefetch for t+2
        if (t + 2 < T_DIM) {
            pk = *(const float2*)kp;
            pq = *(const float2*)qp;
            if (tid < 16) pv = *vp;
        }
        kp += DT; qp += DT; vp += DT;

        f32x2 k2[16], q2[16];
#pragma unroll
        for (int u = 0; u < 8; ++u) {
            f32x4 kv = *(const f32x4*)&ks[cb][rA2 + 4 * u];
            f32x4 qv = *(const f32x4*)&qs[cb][rA2 + 4 * u];
            k2[2*u] = kv.xy; k2[2*u+1] = kv.zw;
            q2[2*u] = qv.xy; q2[2*u+1] = qv.zw;
        }
        const float v0 = vs[cb][g];

        // racc' = sum_j S'_ij k_j : 32 in-thread cols, then 16-lane DPP reduce
        f32x2 p0 = (f32x2)0.0f, p1 = (f32x2)0.0f;
        f32x2 p2 = (f32x2)0.0f, p3 = (f32x2)0.0f;
#pragma unroll
        for (int w = 0; w < 4; ++w) {
            p0 += S2[4*w]     * k2[4*w];
            p1 += S2[4*w + 1] * k2[4*w + 1];
            p2 += S2[4*w + 2] * k2[4*w + 2];
            p3 += S2[4*w + 3] * k2[4*w + 3];
        }
        p0 += p1; p2 += p3; p0 += p2;
        const float racc = reduce16(p0.x + p0.y);

        const float dp = __builtin_fmaf(C_FOLD, v0, -racc);
        const f32x2 d0 = {dp, dp};

        // S'_new = C - 2C/(exp2(S' + dp'*k)+1);  sq' += S'_new * q
        // Grouped rcp (R6): one v_rcp per 8 elems via prefix/suffix products.
        f32x2 sacc0 = (f32x2)0.0f, sacc1 = (f32x2)0.0f;
#pragma unroll
        for (int w = 0; w < 4; ++w) {
            f32x2 a0 = S2[4*w]     + d0 * k2[4*w];
            f32x2 a1 = S2[4*w + 1] + d0 * k2[4*w + 1];
            f32x2 a2 = S2[4*w + 2] + d0 * k2[4*w + 2];
            f32x2 a3 = S2[4*w + 3] + d0 * k2[4*w + 3];
            f32x2 f0 = { __builtin_amdgcn_exp2f(a0.x), __builtin_amdgcn_exp2f(a0.y) };
            f32x2 f1 = { __builtin_amdgcn_exp2f(a1.x), __builtin_amdgcn_exp2f(a1.y) };
            f32x2 f2 = { __builtin_amdgcn_exp2f(a2.x), __builtin_amdgcn_exp2f(a2.y) };
            f32x2 f3 = { __builtin_amdgcn_exp2f(a3.x), __builtin_amdgcn_exp2f(a3.y) };
            f0 = f0 + 1.0f; f1 = f1 + 1.0f; f2 = f2 + 1.0f; f3 = f3 + 1.0f;
            // product tree over the 8 scalars {f0,f1,f2,f3}.{x,y}
            f32x2 m0 = f0 * f1;
            f32x2 m1 = f2 * f3;
            f32x2 qq = m0 * m1;
            float rP = __builtin_amdgcn_rcpf(qq.x * qq.y);
            f32x2 rq  = { qq.y * rP, qq.x * rP };   // {1/qq.x, 1/qq.y}
            f32x2 rm0 = rq * m1;                     // {1/m0.x, 1/m0.y}
            f32x2 rm1 = rq * m0;                     // {1/m1.x, 1/m1.y}
            f32x2 r0 = rm0 * f1;                     // 1/f0
            f32x2 r1 = rm0 * f0;                     // 1/f1
            f32x2 r2 = rm1 * f3;                     // 1/f2
            f32x2 r3 = rm1 * f2;                     // 1/f3
            f32x2 n0 = Cv + r0 * M2Cv;
            f32x2 n1 = Cv + r1 * M2Cv;
            f32x2 n2 = Cv + r2 * M2Cv;
            f32x2 n3 = Cv + r3 * M2Cv;
            S2[4*w] = n0; S2[4*w + 1] = n1; S2[4*w + 2] = n2; S2[4*w + 3] = n3;
            sacc0 += n0 * q2[4*w]     + n2 * q2[4*w + 2];
            sacc1 += n1 * q2[4*w + 1] + n3 * q2[4*w + 3];
        }
        sacc0 += sacc1;
        const float sq = reduce16(sacc0.x + sacc0.y);

        if (l4 == 0) {
            float s0 = sq * INV_C;
            float g0 = __builtin_amdgcn_rcpf(1.0f + __builtin_amdgcn_exp2f(-s0 * 1.44269504f));
            op[0] = s0 * s0 * g0;
        }
        op += DT;
        __syncthreads();
    }

    // S_final (true scale) -> d_out[T*B*N + ((b*N + i)*N + col)]
    const size_t base = (size_t)T_DIM * B_DIM * N_DIM;
    const size_t so = base + ((size_t)b * N_DIM + i0 + g) * N_DIM + 32 * l4;
#pragma unroll
    for (int u = 0; u < 8; ++u) {
        float4 w0;
        w0.x = S2[2*u].x   * INV_C; w0.y = S2[2*u].y   * INV_C;
        w0.z = S2[2*u+1].x * INV_C; w0.w = S2[2*u+1].y * INV_C;
        *(float4*)&out[so + 4 * u] = w0;
    }
}

extern "C" void kernel_launch(void* const* d_in, const int* in_sizes, int n_in,
                              void* d_out, int out_size, void* d_ws, size_t ws_size,
                              hipStream_t stream) {
    const float* x  = (const float*)d_in[0];
    const float* Wk = (const float*)d_in[1];
    const float* Wv = (const float*)d_in[2];
    const float* Wq = (const float*)d_in[3];
    float* outp = (float*)d_out;

    const size_t MN = (size_t)T_DIM * B_DIM * N_DIM;
    float* kbuf = (float*)d_ws;
    float* vbuf = kbuf + MN;
    float* qbuf = vbuf + MN;

    proj_gemm<<<dim3(128, 8), 256, 0, stream>>>(x, Wk, Wv, Wq, kbuf, vbuf, qbuf);
    knorm<<<2048, 256, 0, stream>>>(kbuf);
    scan_kernel<<<dim3(32, 16), 256, 0, stream>>>(kbuf, vbuf, qbuf, outp);
}